// Round 7
// baseline (49.404 us; speedup 1.0000x reference)
//
#include <hip/hip_runtime.h>
#include <hip/hip_bf16.h>

#define Bsz 2048
#define Dim 128
#define Nrows 4096

typedef float f32x4 __attribute__((ext_vector_type(4)));
typedef __bf16 bf16x8 __attribute__((ext_vector_type(8)));

// ws layout: U @0 (1 MiB bf16), rowC @1MiB (256 f32), rowU @1MiB+1K, c1 @1MiB+2K

// K1: normalize [z; z_aug] -> bf16 U (16 rows/block); block 0 counts labels==1
__global__ __launch_bounds__(256) void k_norm(const float* __restrict__ z,
                                              const float* __restrict__ za,
                                              const long long* __restrict__ labels,
                                              __bf16* __restrict__ U,
                                              int* __restrict__ c1out) {
    const int wid = threadIdx.x >> 6, lane = threadIdx.x & 63;
    #pragma unroll
    for (int pass = 0; pass < 4; pass++) {
        const int r = blockIdx.x * 16 + pass * 4 + wid;
        const float* src = (r < Bsz) ? (z + (size_t)r * Dim) : (za + (size_t)(r - Bsz) * Dim);
        float2 x = reinterpret_cast<const float2*>(src)[lane];
        float ss = x.x * x.x + x.y * x.y;
        #pragma unroll
        for (int m = 1; m < 64; m <<= 1) ss += __shfl_xor(ss, m);
        const float sc = 1.0f / fmaxf(sqrtf(ss), 1e-12f);
        __bf16* dst = U + (size_t)r * Dim + 2 * lane;
        dst[0] = (__bf16)(x.x * sc);
        dst[1] = (__bf16)(x.y * sc);
    }
    if (blockIdx.x == 0) {
        __shared__ int ci[256];
        const int t = threadIdx.x;
        int c = 0;
        #pragma unroll
        for (int k = 0; k < 8; k++) c += (int)labels[t * 8 + k];
        ci[t] = c;
        __syncthreads();
        for (int s = 128; s > 0; s >>= 1) {
            if (t < s) ci[t] += ci[t + s];
            __syncthreads();
        }
        if (t == 0) c1out[0] = ci[0];
    }
}

// K2: ROW-COMPLETE swapped-operand Gram. 256 blocks x 1024 thr (16 waves).
// Block owns 16 rows i; wave w owns j-strip [w*256, w*256+256).
// D[j][i] = mfma(A=U_j, B=U_i): i = l15 lane-local -> scalar accumulators,
// j-reduction collapses in-register across the 16 at-tiles. Per-row finalize
// (lnD / uns / sup) happens in LDS inside this kernel -> one (C,U) pair/block.
__global__ __launch_bounds__(1024, 4) void k_gram(const __bf16* __restrict__ U,
                                                  const long long* __restrict__ labels,
                                                  const int* __restrict__ c1p,
                                                  float* __restrict__ rowC,
                                                  float* __restrict__ rowU) {
    const int ibase = blockIdx.x * 16;
    const int w = threadIdx.x >> 6;        // 0..15
    const int lane = threadIdx.x & 63;
    const int l15 = lane & 15, l4 = lane >> 4;
    const int jw = w * 256;                // this wave's j-window base

    __shared__ float sd[16][17], s1[16][17], sa[16][17];
    __shared__ float dpl[16];
    __shared__ float csb[17], usb[17];

    // B fragments = U_i (i-side), resident: 4 ks
    bf16x8 b[4];
    #pragma unroll
    for (int ks = 0; ks < 4; ks++)
        b[ks] = *reinterpret_cast<const bf16x8*>(
            U + (size_t)(ibase + l15) * Dim + ks * 32 + l4 * 8);

    // label bitmasks for the wave's 4 x 64-col groups
    unsigned long long lmask[4];
    #pragma unroll
    for (int g = 0; g < 4; g++)
        lmask[g] = __ballot(labels[(jw + g * 64 + lane) & (Bsz - 1)] == 1);

    float dsum = 0.f, r1s = 0.f, ras = 0.f;
    const float KE1 = 2.8853900817779268f;    // 2*log2(e)
    const float KE0 = -2.8853900817779268f;

    #pragma unroll
    for (int at = 0; at < 16; at++) {
        const int jb = jw + at * 16;
        bf16x8 a[4];
        #pragma unroll
        for (int ks = 0; ks < 4; ks++)
            a[ks] = *reinterpret_cast<const bf16x8*>(
                U + (size_t)(jb + l15) * Dim + ks * 32 + l4 * 8);
        f32x4 acc = {0.f, 0.f, 0.f, 0.f};
        #pragma unroll
        for (int ks = 0; ks < 4; ks++)
            acc = __builtin_amdgcn_mfma_f32_16x16x32_bf16(a[ks], b[ks], acc, 0, 0, 0);
        const bool dg = (jb == ibase);            // tile holds diagonal
        const bool pg = (jb == (ibase ^ 2048));   // tile holds partner cols
        #pragma unroll
        for (int q = 0; q < 4; q++) {
            float av = acc[q];                    // S[j][i]/2 == S[i][j]/2
            const bool sel = (l15 == l4 * 4 + q); // j-local == i-local
            if (pg && sel) dpl[l15] = av;         // S(i, partner)/2
            float e = exp2f(fmaf(av, KE1, KE0));  // exp(S - 2)
            if (dg && sel) { e = 0.f; av = 0.f; } // exclude j == i
            dsum += e;
            ras += av;
            const float labq = (float)((lmask[at >> 2] >> ((at & 3) * 16 + l4 * 4 + q)) & 1ull);
            r1s = fmaf(labq, av, r1s);
        }
    }

    // collapse the 4 l4-groups (j-partition); i = l15 stays lane-local
    {
        float v0 = dsum, v1 = r1s, v2 = ras;
        v0 += __shfl_xor(v0, 16); v0 += __shfl_xor(v0, 32);
        v1 += __shfl_xor(v1, 16); v1 += __shfl_xor(v1, 32);
        v2 += __shfl_xor(v2, 16); v2 += __shfl_xor(v2, 32);
        if (l4 == 0) {
            sd[l15][w] = v0;
            s1[l15][w] = v1;
            sa[l15][w] = v2;
        }
    }
    __syncthreads();

    // wave 0: reduce 16 wave-strips per row, compute per-row loss terms
    if (w == 0) {
        const int r = lane >> 2;      // row 0..15
        const int sg = lane & 3;      // strip group
        float dn = 0.f, v1 = 0.f, va = 0.f;
        #pragma unroll
        for (int k = 0; k < 4; k++) {
            const int s = sg * 4 + k;
            dn += sd[r][s]; v1 += s1[r][s]; va += sa[r][s];
        }
        dn += __shfl_xor(dn, 1); dn += __shfl_xor(dn, 2);
        v1 += __shfl_xor(v1, 1); v1 += __shfl_xor(v1, 2);
        va += __shfl_xor(va, 1); va += __shfl_xor(va, 2);
        float cs = 0.f, us = 0.f;
        if (sg == 0) {
            const int i = ibase + r;
            const long long lb = labels[i & (Bsz - 1)];
            const int c1 = *c1p;
            const float lnD = logf(dn) + 2.0f;        // lse over j != i (row max = 2)
            const float uns = lnD - 2.0f * dpl[r];    // pos = S(i, partner)
            const float cnt = 2.f * (float)((lb == 1) ? c1 : (Bsz - c1));
            const float sumeq = 2.f * ((lb == 1) ? v1 : (va - v1));
            const float sup = lnD - sumeq / (cnt - 1.f);
            cs = (lb == 1) ? sup : uns;
            us = uns;
        }
        #pragma unroll
        for (int m = 1; m < 64; m <<= 1) {
            cs += __shfl_xor(cs, m);
            us += __shfl_xor(us, m);
        }
        if (lane == 0) { rowC[blockIdx.x] = cs; rowU[blockIdx.x] = us; }
    }
}

// K3: combine 256 block results -> scalar loss
__global__ __launch_bounds__(256) void k_comb(const float* __restrict__ rowC,
                                              const float* __restrict__ rowU,
                                              const int* __restrict__ c1p,
                                              float* __restrict__ out) {
    __shared__ float sc[256], su[256];
    const int t = threadIdx.x;
    sc[t] = rowC[t];
    su[t] = rowU[t];
    __syncthreads();
    for (int s = 128; s > 0; s >>= 1) {
        if (t < s) { sc[t] += sc[t + s]; su[t] += su[t + s]; }
        __syncthreads();
    }
    if (t == 0) out[0] = ((*c1p > 0) ? sc[0] : su[0]) / (float)Nrows;
}

extern "C" void kernel_launch(void* const* d_in, const int* in_sizes, int n_in,
                              void* d_out, int out_size, void* d_ws, size_t ws_size,
                              hipStream_t stream) {
    const float* z  = (const float*)d_in[0];
    const float* za = (const float*)d_in[1];
    const long long* labels = (const long long*)d_in[2];

    char* ws = (char*)d_ws;
    __bf16* U    = (__bf16*)(ws);
    float*  rowC = (float*)(ws + (1u << 20));
    float*  rowU = (float*)(ws + (1u << 20) + (1u << 10));
    int*    c1   = (int*)  (ws + (1u << 20) + (2u << 10));
    float*  out  = (float*)d_out;

    hipLaunchKernelGGL(k_norm, dim3(256), dim3(256),  0, stream, z, za, labels, U, c1);
    hipLaunchKernelGGL(k_gram, dim3(256), dim3(1024), 0, stream, U, labels, c1, rowC, rowU);
    hipLaunchKernelGGL(k_comb, dim3(1),   dim3(256),  0, stream, rowC, rowU, c1, out);
}

// Round 8
// 29.686 us; speedup vs baseline: 1.6642x; 1.6642x over previous
//
#include <hip/hip_runtime.h>
#include <hip/hip_bf16.h>

#define Bsz 2048
#define Dim 128
#define Nrows 4096

typedef float f32x4 __attribute__((ext_vector_type(4)));
typedef __bf16 bf16x8 __attribute__((ext_vector_type(8)));

// ws layout:
//   U    @ 0        : 4096*128*2 = 1 MiB (bf16 normalized rows)
//   part @ 1 MiB    : 4096*32*4 = 512 KiB (per (row,jblk) sum exp(S-2), diag excl)
//   rs1p @ 1.5 MiB  : 512 KiB (per (row,jblk) sum lab_j*S/2)
//   rsap @ 2 MiB    : 512 KiB (per (row,jblk) sum S/2)
//   dpv  @ 2.5 MiB  : 16 KiB (S(i,partner)/2)
//   rowC @ 2.5M+16K : 256*4 ; rowU @ +1K ; c1 @ +2K

// K1: normalize [z; z_aug] -> bf16 U (16 rows/block); block 0 counts labels==1
__global__ __launch_bounds__(256) void k_norm(const float* __restrict__ z,
                                              const float* __restrict__ za,
                                              const long long* __restrict__ labels,
                                              __bf16* __restrict__ U,
                                              int* __restrict__ c1out) {
    const int wid = threadIdx.x >> 6, lane = threadIdx.x & 63;
    #pragma unroll
    for (int pass = 0; pass < 4; pass++) {
        const int r = blockIdx.x * 16 + pass * 4 + wid;
        const float* src = (r < Bsz) ? (z + (size_t)r * Dim) : (za + (size_t)(r - Bsz) * Dim);
        float2 x = reinterpret_cast<const float2*>(src)[lane];
        float ss = x.x * x.x + x.y * x.y;
        #pragma unroll
        for (int m = 1; m < 64; m <<= 1) ss += __shfl_xor(ss, m);
        const float sc = 1.0f / fmaxf(sqrtf(ss), 1e-12f);
        __bf16* dst = U + (size_t)r * Dim + 2 * lane;
        dst[0] = (__bf16)(x.x * sc);
        dst[1] = (__bf16)(x.y * sc);
    }
    if (blockIdx.x == 0) {
        __shared__ int ci[256];
        const int t = threadIdx.x;
        int c = 0;
        #pragma unroll
        for (int k = 0; k < 8; k++) c += (int)labels[t * 8 + k];
        ci[t] = c;
        __syncthreads();
        for (int s = 128; s > 0; s >>= 1) {
            if (t < s) ci[t] += ci[t + s];
            __syncthreads();
        }
        if (t == 0) c1out[0] = ci[0];
    }
}

// K2: LDS-staged 128x128 Gram tile with fused epilogue. 1024 blocks x 256 thr.
// Block (iblk,jblk): stage i-panel + j-panel (128 rows x 256B each) into LDS
// with chunk-XOR swizzle LDS[r][p^(r&7)] = G[r][p] (kills the 16-way ds_read
// bank conflict; spread is 2-way = free). Wave w: wi=w&1 (64-i half), wj=w>>1
// (64-j half). Swapped operands D[j][i] = mfma(A=U_j, B=U_i): i = l15 is
// lane-local -> scalar accumulators; j collapses in-register + 2 shuffles.
__global__ __launch_bounds__(256, 2) void k_gram(const __bf16* __restrict__ U,
                                                 const long long* __restrict__ labels,
                                                 float* __restrict__ part,
                                                 float* __restrict__ rs1p,
                                                 float* __restrict__ rsap,
                                                 float* __restrict__ dpv) {
    extern __shared__ __align__(16) char smem[];
    __bf16* Ai = (__bf16*)smem;                 // [128 rows][16 chunks of 8 bf16]
    __bf16* Aj = (__bf16*)smem + 128 * 128;     // j-panel, same layout
    float* red = (float*)smem;                  // aliased post-barrier: [3][2][2][4][16]

    const int iblk = blockIdx.x >> 5, jblk = blockIdx.x & 31;
    const int ibase = iblk * 128, jbase = jblk * 128;
    const int w = threadIdx.x >> 6, lane = threadIdx.x & 63;
    const int wi = w & 1, wj = w >> 1;
    const int l15 = lane & 15, l4 = lane >> 4;

    // ---- stage both panels (coalesced 4 KB global reads; swizzled LDS writes)
    {
        const int p = lane & 15, rsub = lane >> 4;
        #pragma unroll
        for (int it = 0; it < 8; it++) {
            const int rl = w * 32 + it * 4 + rsub;          // local row 0..127
            const int dst = (rl * 16 + (p ^ (rl & 7))) * 8; // swizzled chunk slot
            bf16x8 vi = *reinterpret_cast<const bf16x8*>(U + (size_t)(ibase + rl) * Dim + p * 8);
            bf16x8 vj = *reinterpret_cast<const bf16x8*>(U + (size_t)(jbase + rl) * Dim + p * 8);
            *reinterpret_cast<bf16x8*>(Ai + dst) = vi;
            *reinterpret_cast<bf16x8*>(Aj + dst) = vj;
        }
    }
    __syncthreads();

    // ---- B fragments (i-side), resident: 4 i-tiles x 4 ks
    bf16x8 b[4][4];
    #pragma unroll
    for (int bt = 0; bt < 4; bt++)
        #pragma unroll
        for (int ks = 0; ks < 4; ks++)
            b[bt][ks] = *reinterpret_cast<const bf16x8*>(
                Ai + ((wi * 64 + bt * 16 + l15) * 16 + ((ks * 4 + l4) ^ (l15 & 7))) * 8);

    // label bitmask for this wave's 64 j-cols
    const unsigned long long lmask =
        __ballot(labels[(jbase + wj * 64 + lane) & (Bsz - 1)] == 1);

    float dsum[4] = {0.f, 0.f, 0.f, 0.f};
    float r1s[4]  = {0.f, 0.f, 0.f, 0.f};
    float ras[4]  = {0.f, 0.f, 0.f, 0.f};
    const float KE1 = 2.8853900817779268f;    // 2*log2(e)
    const float KE0 = -2.8853900817779268f;

    #pragma unroll
    for (int at = 0; at < 4; at++) {
        bf16x8 a[4];
        #pragma unroll
        for (int ks = 0; ks < 4; ks++)
            a[ks] = *reinterpret_cast<const bf16x8*>(
                Aj + ((wj * 64 + at * 16 + l15) * 16 + ((ks * 4 + l4) ^ (l15 & 7))) * 8);
        float labq[4];
        #pragma unroll
        for (int q = 0; q < 4; q++)
            labq[q] = (float)((lmask >> (at * 16 + l4 * 4 + q)) & 1ull);
        const int jt = jbase + wj * 64 + at * 16;

        #pragma unroll
        for (int bt = 0; bt < 4; bt++) {
            f32x4 acc = {0.f, 0.f, 0.f, 0.f};
            #pragma unroll
            for (int ks = 0; ks < 4; ks++)
                acc = __builtin_amdgcn_mfma_f32_16x16x32_bf16(a[ks], b[bt][ks], acc, 0, 0, 0);
            const int itl = ibase + wi * 64 + bt * 16;
            const bool dg = (jt == itl);             // tile holds diagonal
            const bool pg = (jt == (itl ^ 2048));    // tile holds partner cols
            #pragma unroll
            for (int q = 0; q < 4; q++) {
                float av = acc[q];                    // S[j][i]/2 == S[i][j]/2
                const bool sel = (l15 == l4 * 4 + q);
                if (pg && sel) dpv[itl + l15] = av;   // S(i, partner)/2
                float e = exp2f(fmaf(av, KE1, KE0));  // exp(S - 2)
                if (dg && sel) { e = 0.f; av = 0.f; } // exclude j == i
                dsum[bt] += e;
                ras[bt] += av;
                r1s[bt] = fmaf(labq[q], av, r1s[bt]);
            }
        }
    }

    // ---- collapse the 4 l4-groups (j-partition); i = l15 stays lane-local
    float o0[4], o1[4], o2[4];
    #pragma unroll
    for (int bt = 0; bt < 4; bt++) {
        float v0 = dsum[bt], v1 = r1s[bt], v2 = ras[bt];
        v0 += __shfl_xor(v0, 16); v0 += __shfl_xor(v0, 32);
        v1 += __shfl_xor(v1, 16); v1 += __shfl_xor(v1, 32);
        v2 += __shfl_xor(v2, 16); v2 += __shfl_xor(v2, 32);
        o0[bt] = v0; o1[bt] = v1; o2[bt] = v2;
    }

    __syncthreads();   // all LDS tile reads done -> safe to alias as `red`
    if (l4 == 0) {
        #pragma unroll
        for (int bt = 0; bt < 4; bt++) {
            red[((0 * 2 + wj) * 2 + wi) * 64 + bt * 16 + l15] = o0[bt];
            red[((1 * 2 + wj) * 2 + wi) * 64 + bt * 16 + l15] = o1[bt];
            red[((2 * 2 + wj) * 2 + wi) * 64 + bt * 16 + l15] = o2[bt];
        }
    }
    __syncthreads();

    // ---- combine the two wj-halves and write per-(row, jblk) partials
    if (threadIdx.x < 128) {
        const int r = threadIdx.x;
        const int rwi = r >> 6, rbt = (r >> 4) & 3, rl15 = r & 15;
        const int row = ibase + r;
        const int base0 = ((0 * 2 + 0) * 2 + rwi) * 64 + rbt * 16 + rl15;
        const int base1 = ((0 * 2 + 1) * 2 + rwi) * 64 + rbt * 16 + rl15;
        part[row * 32 + jblk] = red[base0] + red[base1];
        rs1p[row * 32 + jblk] = red[base0 + 256] + red[base1 + 256];
        rsap[row * 32 + jblk] = red[base0 + 512] + red[base1 + 512];
    }
}

// K3: 256 blocks x 256 thr. Per-row 32-strip reduction + loss -> block partials.
__global__ __launch_bounds__(256) void k_row(const long long* __restrict__ labels,
                                             const int* __restrict__ c1p,
                                             const float* __restrict__ part,
                                             const float* __restrict__ rs1p,
                                             const float* __restrict__ rsap,
                                             const float* __restrict__ dpv,
                                             float* __restrict__ rowC,
                                             float* __restrict__ rowU) {
    const int wid = threadIdx.x >> 6, lane = threadIdx.x & 63;
    const int half = lane >> 5, ls = lane & 31;
    const int c1 = *c1p;
    float cs = 0.f, us = 0.f;
    #pragma unroll
    for (int rr = 0; rr < 2; rr++) {
        const int i = blockIdx.x * 16 + wid * 4 + rr * 2 + half;
        float dn = part[i * 32 + ls];
        float v1 = rs1p[i * 32 + ls];
        float va = rsap[i * 32 + ls];
        #pragma unroll
        for (int m = 1; m < 32; m <<= 1) {
            dn += __shfl_xor(dn, m);
            v1 += __shfl_xor(v1, m);
            va += __shfl_xor(va, m);
        }
        if (ls == 0) {
            const long long lb = labels[i & (Bsz - 1)];
            const float lnD = logf(dn) + 2.0f;        // lse over j != i (row max = 2)
            const float uns = lnD - 2.0f * dpv[i];    // pos = S(i, partner)
            const float cnt = 2.f * (float)((lb == 1) ? c1 : (Bsz - c1));
            const float sumeq = 2.f * ((lb == 1) ? v1 : (va - v1));
            const float sup = lnD - sumeq / (cnt - 1.f);
            cs += (lb == 1) ? sup : uns;
            us += uns;
        }
    }
    cs += __shfl_xor(cs, 32);   // lane 0 <- lane 32 (ls!=0 lanes hold 0)
    us += __shfl_xor(us, 32);
    __shared__ float wcs[4], wus[4];
    if (lane == 0) { wcs[wid] = cs; wus[wid] = us; }
    __syncthreads();
    if (threadIdx.x == 0) {
        rowC[blockIdx.x] = wcs[0] + wcs[1] + wcs[2] + wcs[3];
        rowU[blockIdx.x] = wus[0] + wus[1] + wus[2] + wus[3];
    }
}

// K4: combine 256 block results -> scalar loss
__global__ __launch_bounds__(256) void k_comb(const float* __restrict__ rowC,
                                              const float* __restrict__ rowU,
                                              const int* __restrict__ c1p,
                                              float* __restrict__ out) {
    __shared__ float sc[256], su[256];
    const int t = threadIdx.x;
    sc[t] = rowC[t];
    su[t] = rowU[t];
    __syncthreads();
    for (int s = 128; s > 0; s >>= 1) {
        if (t < s) { sc[t] += sc[t + s]; su[t] += su[t + s]; }
        __syncthreads();
    }
    if (t == 0) out[0] = ((*c1p > 0) ? sc[0] : su[0]) / (float)Nrows;
}

extern "C" void kernel_launch(void* const* d_in, const int* in_sizes, int n_in,
                              void* d_out, int out_size, void* d_ws, size_t ws_size,
                              hipStream_t stream) {
    const float* z  = (const float*)d_in[0];
    const float* za = (const float*)d_in[1];
    const long long* labels = (const long long*)d_in[2];

    char* ws = (char*)d_ws;
    __bf16* U    = (__bf16*)(ws);
    float*  part = (float*)(ws + (1u << 20));
    float*  rs1p = (float*)(ws + (1u << 20) + (512u << 10));
    float*  rsap = (float*)(ws + (2u << 20));
    float*  dpv  = (float*)(ws + (2u << 20) + (512u << 10));
    float*  rowC = (float*)(ws + (2u << 20) + (528u << 10));
    float*  rowU = (float*)(ws + (2u << 20) + (529u << 10));
    int*    c1   = (int*)  (ws + (2u << 20) + (530u << 10));
    float*  out  = (float*)d_out;

    hipLaunchKernelGGL(k_norm, dim3(256),  dim3(256), 0,     stream, z, za, labels, U, c1);
    hipLaunchKernelGGL(k_gram, dim3(1024), dim3(256), 65536, stream, U, labels, part, rs1p, rsap, dpv);
    hipLaunchKernelGGL(k_row,  dim3(256),  dim3(256), 0,     stream, labels, c1, part, rs1p, rsap, dpv, rowC, rowU);
    hipLaunchKernelGGL(k_comb, dim3(1),    dim3(256), 0,     stream, rowC, rowU, c1, out);
}